// Round 5
// baseline (548.666 us; speedup 1.0000x reference)
//
#include <hip/hip_runtime.h>
#include <stdint.h>

// B=8, T=4096, C=1024, NH=64, HD=16. M = B*T = 32768.

typedef __attribute__((ext_vector_type(8))) __bf16 bf16x8;
typedef __attribute__((ext_vector_type(4))) float f32x4;
typedef __attribute__((ext_vector_type(4))) unsigned int u32x4;
typedef __attribute__((ext_vector_type(4))) unsigned short u16x4;

#define AS1 __attribute__((address_space(1)))
#define AS3 __attribute__((address_space(3)))

__device__ __forceinline__ unsigned short f2bf(float f) {
  unsigned int u = __builtin_bit_cast(unsigned int, f);
  u += 0x7FFFu + ((u >> 16) & 1u);
  return (unsigned short)(u >> 16);
}

__device__ __forceinline__ void gl_lds16(const unsigned short* g, unsigned short* l) {
  __builtin_amdgcn_global_load_lds((const AS1 unsigned int*)g, (AS3 unsigned int*)l, 16, 0, 0);
}

// ---------------- fp32 -> bf16 converts ----------------
__global__ __launch_bounds__(256)
void cvt_x(const float* __restrict__ src, unsigned short* __restrict__ dst, int n4) {
  int i = blockIdx.x * blockDim.x + threadIdx.x;
  const int stride = gridDim.x * blockDim.x;
  for (; i < n4; i += stride) {
    f32x4 v = *(const f32x4*)(src + (size_t)i * 4);
    u16x4 o;
    o.x = f2bf(v.x); o.y = f2bf(v.y); o.z = f2bf(v.z); o.w = f2bf(v.w);
    *(u16x4*)(dst + (size_t)i * 4) = o;
  }
}

// Plain stacked bf16 weights: wb = [Wq;Wk;Wv;Wp] as [4096][1024]
__global__ __launch_bounds__(256)
void cvt_w(const float* __restrict__ w0, const float* __restrict__ w1,
           const float* __restrict__ w2, const float* __restrict__ w3,
           unsigned short* __restrict__ dst) {
  const int j = blockIdx.x * 256 + threadIdx.x;     // float4 index within one weight
  const float* ws[4] = {w0, w1, w2, w3};
  #pragma unroll
  for (int r = 0; r < 4; ++r) {
    f32x4 v = *(const f32x4*)(ws[r] + (size_t)j * 4);
    u16x4 o;
    o.x = f2bf(v.x); o.y = f2bf(v.y); o.z = f2bf(v.z); o.w = f2bf(v.w);
    *(u16x4*)(dst + ((size_t)r * 262144 + j) * 4) = o;
  }
}

// =======================================================================
// 256x256-tile, 8-phase pipelined bf16 GEMM (T2+T3+T4+T5 template port)
// out[m][n] = sum_k A[m][k] * W[n][k] + bias[n]
// KIND 0: fused QKV (N=3072), KIND 1: proj (N=1024, fp32 out)
//
// Geometry: BM=BN=256, BK=64; 8 waves = 4(M) x 2(N); per-wave C = 64x128.
// LDS 128KB: buf d (d=0,1) at byte d*65536; A tile [2 halves][128 rows][64 k]
// at +0, B tile at +32768. Half-tile = 16KB = 2 gl_lds per wave.
// Swizzle: 16B slot s at row r holds global k-block (s ^ (r&7)) -> ds_read
// spreads 64 lanes uniformly over all 32 banks; staging source pre-permuted.
//
// Per iter (K-tiles 2i,2i+1): 8 phases. Phase (buf DB, quadrant Q):
//   reads B frags 2Q,2Q+1 (4 ds_read_b128); Q==0 also A frags (8 reads);
//   stage 1 half-tile; barrier; lgkmcnt(0); setprio(1); 16 MFMA; setprio(0);
//   [vmcnt(4) at phases 4,8]; barrier.
// Stage slots: ph1 b1.B0(kt 2i+1), ph2 b1.B1, ph3 b0.A0(2i+2), ph4 b0.A1,
//   ph5 b0.B0(2i+2), ph6 b0.B1, ph7 b1.A0(2i+3), ph8 b1.A1.
// Release audit: buf A released after ph1 (all A reads in ph1) -> ph3+ OK;
//   buf B released after ph4 -> ph5+ OK; cross-wave via per-phase barriers.
// vmcnt audit (2 loads per half-tile per wave; waits only at ph4/ph8):
//   invariant after each wait: exactly 2 half-tiles (4 loads) outstanding.
//   ph8 wait: completes through b0'.B1 (all of next iter's buf0) ✓
//   ph4 wait: completes through b1.B1 (all of this iter's buf1) ✓
// Tail i=7: ph3-8 stages skipped; ph4 wait -> vmcnt(0); ph8 wait skipped.
// =======================================================================

#define WAITLG do { asm volatile("s_waitcnt lgkmcnt(0)" ::: "memory"); \
                    __builtin_amdgcn_sched_barrier(0); } while (0)
#define WAITVM(n) do { asm volatile("s_waitcnt vmcnt(" #n ")" ::: "memory"); \
                       __builtin_amdgcn_sched_barrier(0); } while (0)

#define LDA_(DB, MI, KS) \
  __builtin_bit_cast(bf16x8, *(const u32x4*)(aP + (DB)*65536 + (MI)*2048 + ((KS) ? slot1 : slot0)))
#define LDB_(DB, N16, KS) \
  __builtin_bit_cast(bf16x8, *(const u32x4*)(bP + (DB)*65536 + (N16)*2048 + ((KS) ? slot1 : slot0)))

#define PH(DB, Q, STAGE, TAIL) do {                                         \
  bf16x8 b00 = LDB_(DB, 2*(Q)+0, 0), b01 = LDB_(DB, 2*(Q)+0, 1);            \
  bf16x8 b10 = LDB_(DB, 2*(Q)+1, 0), b11 = LDB_(DB, 2*(Q)+1, 1);            \
  if ((Q) == 0) {                                                           \
    _Pragma("unroll")                                                       \
    for (int mi = 0; mi < 4; ++mi) {                                        \
      aF[mi][0] = LDA_(DB, mi, 0);                                          \
      aF[mi][1] = LDA_(DB, mi, 1);                                          \
    }                                                                       \
  }                                                                         \
  STAGE;                                                                    \
  __builtin_amdgcn_sched_barrier(0);                                        \
  __builtin_amdgcn_s_barrier();                                             \
  WAITLG;                                                                   \
  __builtin_amdgcn_s_setprio(1);                                            \
  _Pragma("unroll")                                                         \
  for (int mi = 0; mi < 4; ++mi) {                                          \
    acc[mi][2*(Q)+0] = __builtin_amdgcn_mfma_f32_16x16x32_bf16(aF[mi][0], b00, acc[mi][2*(Q)+0], 0, 0, 0); \
    acc[mi][2*(Q)+0] = __builtin_amdgcn_mfma_f32_16x16x32_bf16(aF[mi][1], b01, acc[mi][2*(Q)+0], 0, 0, 0); \
    acc[mi][2*(Q)+1] = __builtin_amdgcn_mfma_f32_16x16x32_bf16(aF[mi][0], b10, acc[mi][2*(Q)+1], 0, 0, 0); \
    acc[mi][2*(Q)+1] = __builtin_amdgcn_mfma_f32_16x16x32_bf16(aF[mi][1], b11, acc[mi][2*(Q)+1], 0, 0, 0); \
  }                                                                         \
  __builtin_amdgcn_s_setprio(0);                                            \
  TAIL;                                                                     \
  __builtin_amdgcn_s_barrier();                                             \
} while (0)

template<int KIND>
__global__ __launch_bounds__(512, 2)
void gemm256(const unsigned short* __restrict__ A,
             const unsigned short* __restrict__ W,
             const float* __restrict__ b0, const float* __restrict__ b1,
             const float* __restrict__ b2,
             unsigned short* __restrict__ oq, unsigned short* __restrict__ okT,
             unsigned short* __restrict__ ovT, float* __restrict__ of)
{
  __shared__ __align__(16) unsigned short lds[65536];   // 128 KB

  const int tid  = threadIdx.x;
  const int lane = tid & 63;
  const int wid  = tid >> 6;          // 0..7
  const int wm4  = wid >> 1;          // 0..3 (M)
  const int wn2  = wid & 1;           // 0..1 (N)
  const int fr   = lane & 15;
  const int fg   = lane >> 4;

  // XCD-bijective, L2-chunked block order (4-panel x 3-col chunks per XCD).
  const int flat = blockIdx.x;
  const int xcd  = flat & 7;
  const int vid  = flat >> 3;
  int brow_t, bcol_t;
  if (KIND == 0) {                    // 1536 blocks: per XCD 192 = 4cg x 4pg x 4p x 3c
    const int cg = vid / 48, r1 = vid % 48;
    const int pg = r1 / 12, r2 = r1 % 12;
    brow_t = xcd * 16 + pg * 4 + r2 / 3;
    bcol_t = cg * 3 + r2 % 3;
  } else {                            // 512 blocks: per XCD 64 = 4pg x 4p x 4c
    const int pg = vid >> 4, r1 = vid & 15;
    brow_t = xcd * 16 + pg * 4 + (r1 >> 2);
    bcol_t = r1 & 3;
  }
  const int brow = brow_t * 256;
  const int bcol = bcol_t * 256;

  // staging: wave w instr j covers rows (w*2+j)*8 + (lane>>3) of a 128-row half;
  // dst slot = lane&7 (linear); src k-block = (lane&7) ^ (lane>>3).
  const int sc = ((lane & 7) ^ (lane >> 3)) << 3;
  const unsigned short* a_base = A + (size_t)(brow + wid * 16 + (lane >> 3)) * 1024 + sc;
  const unsigned short* w_base = W + (size_t)(bcol + wid * 16 + (lane >> 3)) * 1024 + sc;

  // ds_read: frag(m16,ks) lane: row = m16*16+fr, slot = (ks*4+fg) ^ (fr&7)
  const int slot0 = ((fg       ^ (fr & 7)) << 4);   // bytes
  const int slot1 = (((4 | fg) ^ (fr & 7)) << 4);
  const char* Lc = (const char*)lds;
  const char* aP = Lc + (wm4 >> 1) * 16384 + ((wm4 & 1) * 64 + fr) * 128;
  const char* bP = Lc + 32768 + wn2 * 16384 + fr * 128;

  // half-tile stages (elements offset off = kt*64)
  auto stA = [&](int off, int buf, int h) {
    const unsigned short* g = a_base + (size_t)h * 131072 + off;
    unsigned short* d = lds + buf * 32768 + h * 8192 + wid * 1024;
    gl_lds16(g, d);
    gl_lds16(g + 8192, d + 512);
  };
  auto stB = [&](int off, int buf, int h) {
    const unsigned short* g = w_base + (size_t)h * 131072 + off;
    unsigned short* d = lds + buf * 32768 + 16384 + h * 8192 + wid * 1024;
    gl_lds16(g, d);
    gl_lds16(g + 8192, d + 512);
  };

  const f32x4 fz = {0.f, 0.f, 0.f, 0.f};
  f32x4 acc[4][8];
  #pragma unroll
  for (int mi = 0; mi < 4; ++mi)
    #pragma unroll
    for (int ni = 0; ni < 8; ++ni) acc[mi][ni] = fz;
  bf16x8 aF[4][2];

  // prologue: b0.A0,A1,B0,B1 (kt0), b1.A0,A1 (kt1) = 12 loads; vmcnt(4)
  // completes buf0 entirely, leaves b1.A0,A1 in flight (steady invariant).
  stA(0, 0, 0); stA(0, 0, 1); stB(0, 0, 0); stB(0, 0, 1);
  stA(64, 1, 0); stA(64, 1, 1);
  WAITVM(4);
  __builtin_amdgcn_s_barrier();

  for (int i = 0; i < 8; ++i) {
    const int off = i * 128;
    const bool nl = (i < 7);
    PH(0, 0, { stB(off + 64, 1, 0); }, {});
    PH(0, 1, { stB(off + 64, 1, 1); }, {});
    PH(0, 2, { if (nl) stA(off + 128, 0, 0); }, {});
    PH(0, 3, { if (nl) stA(off + 128, 0, 1); },
             { if (nl) { WAITVM(4); } else { WAITVM(0); } });
    PH(1, 0, { if (nl) stB(off + 128, 0, 0); }, {});
    PH(1, 1, { if (nl) stB(off + 128, 0, 1); }, {});
    PH(1, 2, { if (nl) stA(off + 192, 1, 0); }, {});
    PH(1, 3, { if (nl) stA(off + 192, 1, 1); },
             { if (nl) { WAITVM(4); } });
  }

  // ---------------- epilogue ----------------
  const int sec = (KIND == 0) ? (bcol >> 10) : 0;
  const float* bias = (KIND == 1) ? b0 : (sec == 0 ? b0 : (sec == 1 ? b1 : b2));

  #pragma unroll
  for (int n16 = 0; n16 < 8; ++n16) {
    const int n_glob = bcol + wn2 * 128 + n16 * 16 + fr;
    const int nn = (KIND == 0) ? (n_glob & 1023) : n_glob;
    const float bv = bias[nn];
    #pragma unroll
    for (int mi = 0; mi < 4; ++mi) {
      const int m0 = brow + wm4 * 64 + mi * 16 + fg * 4;
      float vals[4];
      #pragma unroll
      for (int r2 = 0; r2 < 4; ++r2) vals[r2] = acc[mi][n16][r2] + bv;

      if (KIND == 0 && sec <= 1) {
        // softmax over the 16 columns (one head's HD) of this fragment
        #pragma unroll
        for (int r2 = 0; r2 < 4; ++r2) {
          float x = vals[r2];
          float mx = x;
          #pragma unroll
          for (int s = 1; s < 16; s <<= 1) mx = fmaxf(mx, __shfl_xor(mx, s, 64));
          float e = __expf(x - mx);
          float sm = e;
          #pragma unroll
          for (int s = 1; s < 16; s <<= 1) sm += __shfl_xor(sm, s, 64);
          vals[r2] = e / sm;
        }
      }

      if (KIND == 1) {
        #pragma unroll
        for (int r2 = 0; r2 < 4; ++r2)
          of[(size_t)(m0 + r2) * 1024 + n_glob] = vals[r2];
      } else if (sec == 0) {
        #pragma unroll
        for (int r2 = 0; r2 < 4; ++r2)
          oq[(size_t)(m0 + r2) * 1024 + nn] = f2bf(vals[r2]);
      } else {
        // transposed per head: dst[((b*64+h)*16+d)*4096 + t]
        unsigned short* o = (sec == 1) ? okT : ovT;
        const int bb = m0 >> 12;
        const int t0 = m0 & 4095;
        const int hh = nn >> 4;
        const int dd = nn & 15;
        u16x4 pk;
        pk.x = f2bf(vals[0]); pk.y = f2bf(vals[1]);
        pk.z = f2bf(vals[2]); pk.w = f2bf(vals[3]);
        *(u16x4*)&o[(((size_t)bb * 64 + hh) * 16 + dd) * 4096 + t0] = pk;
      }
    }
  }
}

// ---------------- per-head linear-attention middle ----------------
__global__ __launch_bounds__(256)
void attn_kernel(const unsigned short* __restrict__ qb,
                 const unsigned short* __restrict__ kT,
                 const unsigned short* __restrict__ vT,
                 unsigned short* __restrict__ yb)
{
  const int head = blockIdx.x;           // b*64 + h
  const int tid  = threadIdx.x;
  const int lane = tid & 63;
  const int wid  = tid >> 6;
  const int fr   = lane & 15;
  const int fg   = lane >> 4;

  const unsigned short* kTh = kT + (size_t)head * 16 * 4096;
  const unsigned short* vTh = vT + (size_t)head * 16 * 4096;

  const u32x4 uz = {0u, 0u, 0u, 0u};
  const f32x4 fz = {0.f, 0.f, 0.f, 0.f};
  const u32x4 uo = {0x3F803F80u, 0x3F803F80u, 0x3F803F80u, 0x3F803F80u};
  const bf16x8 ones = __builtin_bit_cast(bf16x8, uo);

  f32x4 cctx = fz, ckc = fz;
  #pragma unroll 4
  for (int t0 = wid * 1024; t0 < (wid + 1) * 1024; t0 += 32) {
    bf16x8 ak = __builtin_bit_cast(bf16x8, *(const u32x4*)&kTh[(size_t)fr * 4096 + t0 + fg * 8]);
    bf16x8 bv = __builtin_bit_cast(bf16x8, *(const u32x4*)&vTh[(size_t)fr * 4096 + t0 + fg * 8]);
    cctx = __builtin_amdgcn_mfma_f32_16x16x32_bf16(ak, bv, cctx, 0, 0, 0);
    ckc  = __builtin_amdgcn_mfma_f32_16x16x32_bf16(ak, ones, ckc, 0, 0, 0);
  }

  __shared__ float red[4][16][16];
  __shared__ float kcr[4][16];
  __shared__ float ctxf[16][16];
  __shared__ float kcf[16];

  #pragma unroll
  for (int r = 0; r < 4; ++r) red[wid][fg * 4 + r][fr] = cctx[r];
  if (fr == 0) {
    #pragma unroll
    for (int r = 0; r < 4; ++r) kcr[wid][fg * 4 + r] = ckc[r];
  }
  __syncthreads();
  {
    const int d = tid >> 4, e = tid & 15;
    ctxf[d][e] = red[0][d][e] + red[1][d][e] + red[2][d][e] + red[3][d][e];
    if (tid < 16) kcf[tid] = kcr[0][tid] + kcr[1][tid] + kcr[2][tid] + kcr[3][tid];
  }
  __syncthreads();

  bf16x8 bctx = __builtin_bit_cast(bf16x8, uz);
  bf16x8 bkc  = __builtin_bit_cast(bf16x8, uz);
  if (fg < 2) {
    #pragma unroll
    for (int j = 0; j < 8; ++j) {
      const int d = fg * 8 + j;
      bctx[j] = (__bf16)ctxf[d][fr];
      bkc[j]  = (__bf16)kcf[d];
    }
  }

  const int b = head >> 6;
  const int h = head & 63;
  const size_t qbase = (size_t)b * 4096 * 1024 + (size_t)h * 16;

  for (int step = 0; step < 64; ++step) {
    const int t0 = step * 64 + wid * 16;
    bf16x8 af = __builtin_bit_cast(bf16x8, uz);
    if (fg < 2)
      af = __builtin_bit_cast(bf16x8, *(const u32x4*)&qb[qbase + (size_t)(t0 + fr) * 1024 + fg * 8]);
    f32x4 cy = __builtin_amdgcn_mfma_f32_16x16x32_bf16(af, bctx, fz, 0, 0, 0);
    f32x4 cd = __builtin_amdgcn_mfma_f32_16x16x32_bf16(af, bkc,  fz, 0, 0, 0);
    #pragma unroll
    for (int r = 0; r < 4; ++r) {
      const int t = t0 + fg * 4 + r;
      const float yv = cy[r] * __builtin_amdgcn_rcpf(cd[r]);
      yb[qbase + (size_t)t * 1024 + fr] = f2bf(yv);
    }
  }
}

// ---------------- launch ----------------
extern "C" void kernel_launch(void* const* d_in, const int* in_sizes, int n_in,
                              void* d_out, int out_size, void* d_ws, size_t ws_size,
                              hipStream_t stream)
{
  (void)in_sizes; (void)n_in; (void)out_size; (void)ws_size;
  const float* x  = (const float*)d_in[0];
  const float* Wq = (const float*)d_in[1];
  const float* bq = (const float*)d_in[2];
  const float* Wk = (const float*)d_in[3];
  const float* bk = (const float*)d_in[4];
  const float* Wv = (const float*)d_in[5];
  const float* bv = (const float*)d_in[6];
  const float* Wp = (const float*)d_in[7];
  const float* bp = (const float*)d_in[8];

  char* ws = (char*)d_ws;
  // requires ws_size >= 276,824,064 bytes
  unsigned short* xb  = (unsigned short*)(ws);              // 67108864 B; reused as yb
  unsigned short* wb  = (unsigned short*)(ws + 67108864);   // 4 x 2097152 B (stacked)
  unsigned short* qb  = (unsigned short*)(ws + 75497472);   // 67108864 B
  unsigned short* kTb = (unsigned short*)(ws + 142606336);  // 67108864 B
  unsigned short* vTb = (unsigned short*)(ws + 209715200);  // 67108864 B

  cvt_x<<<2048, 256, 0, stream>>>(x, xb, 33554432 / 4);
  cvt_w<<<1024, 256, 0, stream>>>(Wq, Wk, Wv, Wp, wb);

  gemm256<0><<<1536, 512, 0, stream>>>(xb, wb, bq, bk, bv, qb, kTb, vTb, nullptr);

  attn_kernel<<<512, 256, 0, stream>>>(qb, kTb, vTb, xb /* = yb */);

  gemm256<1><<<512, 512, 0, stream>>>(xb /* yb */, wb + 3145728, bp, bp, bp,
                                      nullptr, nullptr, nullptr, (float*)d_out);
}